// Round 1
// baseline (279.495 us; speedup 1.0000x reference)
//
#include <hip/hip_runtime.h>
#include <hip/hip_bf16.h>
#include <string.h>

// CausalSelfAttention on MI355X (gfx950), bf16 MFMA pipeline.
// R10: attention rebuilt around two levers (theory: LDS-pipe + barrier-drain
//   latency bound, per rocprof MfmaUtil 19.5 / VALUBusy 47.5 / round=5600cyc):
//   (a) P^T LDS round-trip replaced by in-register cvt_pk + permlane16/32_swap
//       redistribution (keys 4g..4g+3/lane -> 8g..8g+7/lane), -6 LDS ops and
//       -2 LDS latency hops per wave-round, -16KB LDS;
//   (b) 3-deep K/V pipeline with counted vmcnt: prefetch issued 2 rounds ahead,
//       raw s_barrier + s_waitcnt vmcnt(2) (never drain to 0 in the loop).
//   Plus s_setprio(1) around MFMA clusters and bijective XCD swizzle on GEMMs.
// D=1024, H=16, Hd=64, B=4, T=2048.

typedef unsigned short u16;
typedef unsigned int u32;
typedef __bf16 bf16x8 __attribute__((ext_vector_type(8)));
typedef float f32x4 __attribute__((ext_vector_type(4)));
typedef unsigned int u32x2 __attribute__((ext_vector_type(2)));

#define MFMA16(a, b, c) __builtin_amdgcn_mfma_f32_16x16x32_bf16((a), (b), (c), 0, 0, 0)

__device__ __forceinline__ u16 f2bf(float f) {
  unsigned u = __float_as_uint(f);
  u += 0x7fffu + ((u >> 16) & 1u);  // RNE
  return (u16)(u >> 16);
}

__device__ __forceinline__ u32 pk2bf(float a, float b) {
  __hip_bfloat162 h = __float22bfloat162_rn(make_float2(a, b));  // v_cvt_pk_bf16_f32
  u32 r;
  memcpy(&r, &h, 4);  // register-level no-op
  return r;
}

__device__ __forceinline__ void gload_lds16(const void* g, void* l) {
  __builtin_amdgcn_global_load_lds((const __attribute__((address_space(1))) void*)g,
                                   (__attribute__((address_space(3))) void*)l, 16, 0, 0);
}

__device__ __forceinline__ u32x2 pl16swap(u32 a, u32 b) {
  // rows = 16-lane groups: a'[g1]=b[g0], a'[g3]=b[g2]; b'[g0]=a[g1], b'[g2]=a[g3]
  return __builtin_amdgcn_permlane16_swap(a, b, false, false);
}
__device__ __forceinline__ u32x2 pl32swap(u32 a, u32 b) {
  // a'[lanes32-63]=b[lanes0-31]; b'[lanes0-31]=a[lanes32-63]
  return __builtin_amdgcn_permlane32_swap(a, b, false, false);
}
__device__ __forceinline__ bf16x8 mkfrag(u32 w0, u32 w1, u32 w2, u32 w3) {
  union { u32 w[4]; bf16x8 v; } u;
  u.w[0] = w0; u.w[1] = w1; u.w[2] = w2; u.w[3] = w3;
  return u.v;
}

// ---------------- cast x (fp32 -> bf16), 4 elems/thread ----------------
__global__ __launch_bounds__(256) void cast_x_kernel(const float* __restrict__ x,
                                                     u16* __restrict__ xb) {
  int i = blockIdx.x * 256 + threadIdx.x;
  float4 v = ((const float4*)x)[i];
  ushort4 o;
  o.x = f2bf(v.x); o.y = f2bf(v.y); o.z = f2bf(v.z); o.w = f2bf(v.w);
  ((ushort4*)xb)[i] = o;
}

// ---------------- transpose-cast W [K][N] fp32 -> Wt [N][K] bf16 ----------------
__global__ __launch_bounds__(256) void tcast_kernel(const float* __restrict__ W,
                                                    u16* __restrict__ Wt, int K, int N) {
  __shared__ float tile[32][33];
  int n0 = blockIdx.x * 32, k0 = blockIdx.y * 32;
  int tx = threadIdx.x & 31, ty = threadIdx.x >> 5;  // 32 x 8
#pragma unroll
  for (int i = 0; i < 4; i++) {
    int k = ty + i * 8;
    tile[k][tx] = W[(size_t)(k0 + k) * N + n0 + tx];
  }
  __syncthreads();
#pragma unroll
  for (int i = 0; i < 4; i++) {
    int n = ty + i * 8;
    Wt[(size_t)(n0 + n) * K + k0 + tx] = f2bf(tile[tx][n]);
  }
}

// ---------------- QKV GEMM: C[8192][3072] = xb @ Wqkvt^T + bias, scatter to Q/K/V ----------------
// Q (first 1024 output cols) additionally scaled by log2(e)/8 so attention can
// use raw v_exp_f32 (= 2^x) with no per-score multiply.
__global__ __launch_bounds__(256) void gemm_qkv_kernel(const u16* __restrict__ A,
                                                       const u16* __restrict__ Bt,
                                                       const float* __restrict__ bias,
                                                       u16* __restrict__ QKV) {
  __shared__ u16 As[128 * 32];
  __shared__ u16 Bs[128 * 32];
  const int tid = threadIdx.x, w = tid >> 6, lane = tid & 63;
  const int g = lane >> 4, c = lane & 15;
  const int wr = w >> 1, wc = w & 1;
  // XCD-aware bijective swizzle (nwg = 24*64 = 1536, %8==0): each XCD gets a
  // contiguous chunk of tile-ids -> consecutive n-tiles share the A panel in L2.
  const int nwg = gridDim.x * gridDim.y;
  const int flat = blockIdx.y * gridDim.x + blockIdx.x;
  const int swz = (flat & 7) * (nwg >> 3) + (flat >> 3);
  const int m0 = (swz / gridDim.x) * 128, n0 = (swz % gridDim.x) * 128;
  const int r4 = lane >> 2, c4 = lane & 3;

  f32x4 acc[4][4];
#pragma unroll
  for (int i = 0; i < 4; i++)
#pragma unroll
    for (int j = 0; j < 4; j++) acc[i][j] = (f32x4){0.f, 0.f, 0.f, 0.f};

  for (int k0 = 0; k0 < 1024; k0 += 32) {
    __syncthreads();
#pragma unroll
    for (int i = 0; i < 2; i++) {
      int rowb = w * 32 + i * 16;
      gload_lds16(A + (size_t)(m0 + rowb + r4) * 1024 + k0 + c4 * 8,
                  (char*)As + rowb * 64);
      gload_lds16(Bt + (size_t)(n0 + rowb + r4) * 1024 + k0 + c4 * 8,
                  (char*)Bs + rowb * 64);
    }
    __syncthreads();

    bf16x8 af[4], bf[4];
#pragma unroll
    for (int mt = 0; mt < 4; mt++)
      af[mt] = *(const bf16x8*)(As + (wr * 64 + mt * 16 + c) * 32 + g * 8);
#pragma unroll
    for (int nt = 0; nt < 4; nt++)
      bf[nt] = *(const bf16x8*)(Bs + (wc * 64 + nt * 16 + c) * 32 + g * 8);
#pragma unroll
    for (int mt = 0; mt < 4; mt++)
#pragma unroll
      for (int nt = 0; nt < 4; nt++) acc[mt][nt] = MFMA16(af[mt], bf[nt], acc[mt][nt]);
  }

  const float qscale = (n0 < 1024) ? 0.18033688011112042f : 1.0f;  // log2(e)/8
  float bn[4];
#pragma unroll
  for (int nt = 0; nt < 4; nt++) bn[nt] = bias[n0 + wc * 64 + nt * 16 + c];
#pragma unroll
  for (int mt = 0; mt < 4; mt++) {
#pragma unroll
    for (int r = 0; r < 4; r++) {
      int m = m0 + wr * 64 + mt * 16 + g * 4 + r;  // token index
      int bb = m >> 11, t = m & 2047;
#pragma unroll
      for (int nt = 0; nt < 4; nt++) {
        int n = n0 + wc * 64 + nt * 16 + c;
        int which = n >> 10, rem = n & 1023, h = rem >> 6, d = rem & 63;
        float v = (acc[mt][nt][r] + bn[nt]) * qscale;
        QKV[(size_t)which * 8388608 + (((size_t)(bb * 16 + h) * 2048 + t) * 64 + d)] = f2bf(v);
      }
    }
  }
}

// ---------------- V transpose: V[bh][2048][64] -> Vt tiled [bh][kt][64d][64k] ----------------
__global__ __launch_bounds__(256) void vtrans_kernel(const u16* __restrict__ V,
                                                     u16* __restrict__ Vt) {
  __shared__ u16 tile[64][65];
  int bh = blockIdx.y;
  int kt = blockIdx.x;
  int t0 = kt * 64;
  int tx = threadIdx.x & 63, ty = threadIdx.x >> 6;  // 64 x 4
  const u16* src = V + ((size_t)bh * 2048 + t0) * 64;
#pragma unroll
  for (int i = 0; i < 16; i++) {
    int tr = i * 4 + ty;
    tile[tr][tx] = src[tr * 64 + tx];
  }
  __syncthreads();
  u16* dst = Vt + ((size_t)(bh * 32 + kt)) * 4096;  // [64d][64k] tile
#pragma unroll
  for (int i = 0; i < 16; i++) {
    int d = i * 4 + ty;
    dst[d * 64 + tx] = tile[tx][d];
  }
}

// ---------------- flash attention: paired 128-row q-tiles, 8 waves x 16 q-rows ----------------
// grid (8 pairs, 16 heads, 4 batch), 512 threads (8 waves). Block handles
// q-tiles p and 15-p (128 rows each) sequentially: 34 uniform rounds.
// R10 structure: K/V staged in a 3-deep LDS ring, prefetch issued 2 rounds
// ahead; round top = s_waitcnt vmcnt(2) (own loads for this round done) + raw
// s_barrier (cross-wave). vmcnt never drained to 0 in the main loop.
// S^T = mfma(K, Q); p = exp2(s) (Q pre-scaled by log2e/8); P^T -> B-frag
// redistribution fully in-register via cvt_pk + permlane32/16_swap; l via
// ones-MFMA psum.
__global__ __launch_bounds__(512, 4) void attn_kernel(const u16* __restrict__ Q,
                                                      const u16* __restrict__ K,
                                                      const u16* __restrict__ Vt,
                                                      u16* __restrict__ ctx) {
  const int pr = blockIdx.x;          // 0..7
  const int qtA = pr, qtB = 15 - pr;  // paired 128-row q-tiles
  const int h = blockIdx.y, b = blockIdx.z;
  const int bh = b * 16 + h;
  const int tid = threadIdx.x, w = tid >> 6, lane = tid & 63;
  const int g = lane >> 4, c = lane & 15;

  const u16* Kg = K + (size_t)bh * 2048 * 64;   // [T][64]
  const u16* Vg = Vt + (size_t)bh * 32 * 4096;  // tiled [kt][64d][64k]

  __shared__ u16 Ks[3][64 * 64];  // K ring, XOR-swizzled chunks (24 KB)
  __shared__ u16 Vs[3][64 * 64];  // V ring (24 KB)

  // staging lane map (verified swizzle); wave w stages rows w*8..w*8+8
  const int srow = lane >> 3;
  const int schunk = (lane & 7) ^ (srow & 7);
  const int cx = c & 7;
  const int off0 = ((g ^ cx) * 8);        // chunk g   (u16 offset)
  const int off1 = (((g ^ cx) ^ 4) * 8);  // chunk g^4
  const int rbase = w * 8;
  const u16* stK = Kg + (size_t)(rbase + srow) * 64 + schunk * 8;
  const u16* stV = Vg + (size_t)(rbase + srow) * 64 + schunk * 8;

  // constant all-ones A-fragment for the psum MFMA
  bf16x8 onesf;
#pragma unroll
  for (int i = 0; i < 8; i++) onesf[i] = (__bf16)1.0f;

  // Q B-fragments for tile A (wave's 16 q-rows; dims 0-31 / 32-63)
  const u16* QgA = Q + ((size_t)bh * 2048 + qtA * 128) * 64;
  bf16x8 aq0 = *(const bf16x8*)(QgA + (w * 16 + c) * 64 + g * 8);
  bf16x8 aq1 = *(const bf16x8*)(QgA + (w * 16 + c) * 64 + 32 + g * 8);

  // prologue: stage K/V tiles for rounds 0 and 1 (tile A kt=0,1; nA>=2 always)
  gload_lds16(stK, (char*)(Ks[0]) + rbase * 128);
  gload_lds16(stV, (char*)(Vs[0]) + rbase * 128);
  gload_lds16(stK + 4096, (char*)(Ks[1]) + rbase * 128);
  gload_lds16(stV + 4096, (char*)(Vs[1]) + rbase * 128);

  f32x4 o[4], la;
#pragma unroll
  for (int nt = 0; nt < 4; nt++) o[nt] = (f32x4){0.f, 0.f, 0.f, 0.f};
  la = (f32x4){0.f, 0.f, 0.f, 0.f};

  const int nA = 2 * qtA + 2;  // rounds in tile A

  // normalize + packed 8B stores for one finished q-tile (wave's 16 rows)
  auto store_tile = [&](int qbase) {
    float inv = 1.f / la[0];
    int q = qbase + w * 16 + c;
    size_t base = ((size_t)(b * 2048 + q)) * 1024 + h * 64;
#pragma unroll
    for (int nt = 0; nt < 4; nt++) {
      u32 lo = pk2bf(o[nt][0] * inv, o[nt][1] * inv);
      u32 hi = pk2bf(o[nt][2] * inv, o[nt][3] * inv);
      *(uint2*)(ctx + base + nt * 16 + g * 4) = make_uint2(lo, hi);
    }
  };

  int cb = 0;  // ring slot for round r (r % 3, maintained incrementally)

  for (int r = 0; r < 34; r++) {
    // Round-top protocol: own loads for THIS round (issued 2 rounds ago) must
    // be done -> wait vmcnt(2) (the 2 newest = next round's loads stay in
    // flight); then raw barrier so every wave's staging rows are valid.
    if (r < 33) {
      asm volatile("s_waitcnt vmcnt(2)" ::: "memory");
    } else {
      asm volatile("s_waitcnt vmcnt(0)" ::: "memory");  // last round: only its 2 left
    }
    __builtin_amdgcn_s_barrier();
    asm volatile("" ::: "memory");  // pin LDS reads/prefetch writes behind the barrier

    // prefetch round r+2's K/V tile into ring slot (cb+2)%3. Safe: all waves
    // passed the barrier above, so round r-1 (same slot) reads are complete.
    if (r < 32) {
      const int rr = r + 2;
      const int ktn = (rr < nA) ? rr : rr - nA;
      int pb = cb + 2; if (pb >= 3) pb -= 3;
      gload_lds16(stK + (size_t)ktn * 4096, (char*)(Ks[pb]) + rbase * 128);
      gload_lds16(stV + (size_t)ktn * 4096, (char*)(Vs[pb]) + rbase * 128);
    }

    const bool inA = (r < nA);
    const int kt = inA ? r : (r - nA);
    const int qbase = inA ? qtA * 128 : qtB * 128;
    const int sb0 = qbase + w * 16;  // wave's first q-row
    const int kb = kt * 64;          // round's first key

    if (kb <= sb0 + 15) {  // wave-uniform: wave live this round
      const u16* Kb = Ks[cb];
      const u16* Vb = Vs[cb];

      // ---- S^T = K . Q^T : 4 key-tiles ----
      __builtin_amdgcn_s_setprio(1);
      f32x4 sa[4];
#pragma unroll
      for (int nt = 0; nt < 4; nt++) {
        bf16x8 k0 = *(const bf16x8*)(Kb + (nt * 16 + c) * 64 + off0);
        bf16x8 k1 = *(const bf16x8*)(Kb + (nt * 16 + c) * 64 + off1);
        f32x4 z = (f32x4){0.f, 0.f, 0.f, 0.f};
        z = MFMA16(k0, aq0, z);  // A=K, B=Q -> S^T[key][q]
        z = MFMA16(k1, aq1, z);
        sa[nt] = z;
      }
      __builtin_amdgcn_s_setprio(0);

      // ---- p = exp2(s) (lane holds keys nt*16+4g..+3 for q-col c) ----
      const bool domask = (kb + 63 > sb0);
      float pe[4][4];
#pragma unroll
      for (int nt = 0; nt < 4; nt++)
#pragma unroll
        for (int rr = 0; rr < 4; rr++) {
          float t = sa[nt][rr];
          if (domask && (kb + nt * 16 + g * 4 + rr) > (sb0 + c)) t = -1e30f;
          pe[nt][rr] = __builtin_amdgcn_exp2f(t);
        }

      // ---- in-register P^T -> B-frag redistribution (replaces LDS round-trip)
      // source lane (g,c): key-pair words W(2g),W(2g+1) of each 16-key tile;
      // dest lane (g,c) needs words W(4g..4g+3) of each 32-key half.
      // {w0,w2} = pl16swap(pl32swap(A_lo, A_hi)) and same for the odd words.
      u32 wA[4], wB[4];
#pragma unroll
      for (int nt = 0; nt < 4; nt++) {
        wA[nt] = pk2bf(pe[nt][0], pe[nt][1]);  // keys 4g+0,4g+1
        wB[nt] = pk2bf(pe[nt][2], pe[nt][3]);  // keys 4g+2,4g+3
      }
      u32x2 xa0 = pl32swap(wA[0], wA[1]);
      u32x2 xb0 = pl32swap(wB[0], wB[1]);
      u32x2 ya0 = pl16swap(xa0[0], xa0[1]);  // [0]=dword0 (keys 8g+0,1), [1]=dword2
      u32x2 yb0 = pl16swap(xb0[0], xb0[1]);  // [0]=dword1, [1]=dword3
      bf16x8 pB0 = mkfrag(ya0[0], yb0[0], ya0[1], yb0[1]);  // keys 8g..8g+7, q=c
      u32x2 xa1 = pl32swap(wA[2], wA[3]);
      u32x2 xb1 = pl32swap(wB[2], wB[3]);
      u32x2 ya1 = pl16swap(xa1[0], xa1[1]);
      u32x2 yb1 = pl16swap(xb1[0], xb1[1]);
      bf16x8 pB1 = mkfrag(ya1[0], yb1[0], ya1[1], yb1[1]);  // keys 32+8g..+7

      // ---- l += P @ 1 on the MFMA pipe; O^T += V^T . P^T : 4 d-tiles ----
      __builtin_amdgcn_s_setprio(1);
      la = MFMA16(onesf, pB0, la);
      la = MFMA16(onesf, pB1, la);
#pragma unroll
      for (int nt = 0; nt < 4; nt++) {
        bf16x8 v0 = *(const bf16x8*)(Vb + (nt * 16 + c) * 64 + off0);
        bf16x8 v1 = *(const bf16x8*)(Vb + (nt * 16 + c) * 64 + off1);
        o[nt] = MFMA16(v0, pB0, o[nt]);
        o[nt] = MFMA16(v1, pB1, o[nt]);
      }
      __builtin_amdgcn_s_setprio(0);
    }

    // transition: tile A finished -> store, reset, swap to tile B's Q
    if (r == nA - 1) {
      store_tile(qtA * 128);
#pragma unroll
      for (int nt = 0; nt < 4; nt++) o[nt] = (f32x4){0.f, 0.f, 0.f, 0.f};
      la = (f32x4){0.f, 0.f, 0.f, 0.f};
      const u16* QgB = Q + ((size_t)bh * 2048 + qtB * 128) * 64;
      aq0 = *(const bf16x8*)(QgB + (w * 16 + c) * 64 + g * 8);
      aq1 = *(const bf16x8*)(QgB + (w * 16 + c) * 64 + 32 + g * 8);
    }

    cb++; if (cb == 3) cb = 0;
  }

  store_tile(qtB * 128);
}

// ---------------- out-proj GEMM: out[8192][1024] = ctx @ Woutt^T + bias (fp32 out) ----------------
__global__ __launch_bounds__(256) void gemm_proj_kernel(const u16* __restrict__ A,
                                                        const u16* __restrict__ Bt,
                                                        const float* __restrict__ bias,
                                                        float* __restrict__ out) {
  __shared__ u16 As[128 * 32];
  __shared__ u16 Bs[128 * 32];
  const int tid = threadIdx.x, w = tid >> 6, lane = tid & 63;
  const int g = lane >> 4, c = lane & 15;
  const int wr = w >> 1, wc = w & 1;
  // XCD-aware bijective swizzle (nwg = 8*64 = 512, %8==0)
  const int nwg = gridDim.x * gridDim.y;
  const int flat = blockIdx.y * gridDim.x + blockIdx.x;
  const int swz = (flat & 7) * (nwg >> 3) + (flat >> 3);
  const int m0 = (swz / gridDim.x) * 128, n0 = (swz % gridDim.x) * 128;
  const int r4 = lane >> 2, c4 = lane & 3;

  f32x4 acc[4][4];
#pragma unroll
  for (int i = 0; i < 4; i++)
#pragma unroll
    for (int j = 0; j < 4; j++) acc[i][j] = (f32x4){0.f, 0.f, 0.f, 0.f};

  for (int k0 = 0; k0 < 1024; k0 += 32) {
    __syncthreads();
#pragma unroll
    for (int i = 0; i < 2; i++) {
      int rowb = w * 32 + i * 16;
      gload_lds16(A + (size_t)(m0 + rowb + r4) * 1024 + k0 + c4 * 8,
                  (char*)As + rowb * 64);
      gload_lds16(Bt + (size_t)(n0 + rowb + r4) * 1024 + k0 + c4 * 8,
                  (char*)Bs + rowb * 64);
    }
    __syncthreads();

    bf16x8 af[4], bf[4];
#pragma unroll
    for (int mt = 0; mt < 4; mt++)
      af[mt] = *(const bf16x8*)(As + (wr * 64 + mt * 16 + c) * 32 + g * 8);
#pragma unroll
    for (int nt = 0; nt < 4; nt++)
      bf[nt] = *(const bf16x8*)(Bs + (wc * 64 + nt * 16 + c) * 32 + g * 8);
#pragma unroll
    for (int mt = 0; mt < 4; mt++)
#pragma unroll
      for (int nt = 0; nt < 4; nt++) acc[mt][nt] = MFMA16(af[mt], bf[nt], acc[mt][nt]);
  }

  float bn[4];
#pragma unroll
  for (int nt = 0; nt < 4; nt++) bn[nt] = bias[n0 + wc * 64 + nt * 16 + c];
#pragma unroll
  for (int mt = 0; mt < 4; mt++)
#pragma unroll
    for (int r = 0; r < 4; r++) {
      int m = m0 + wr * 64 + mt * 16 + g * 4 + r;
#pragma unroll
      for (int nt = 0; nt < 4; nt++) {
        int n = n0 + wc * 64 + nt * 16 + c;
        out[(size_t)m * 1024 + n] = acc[mt][nt][r] + bn[nt];
      }
    }
}

// ---------------- launch ----------------
extern "C" void kernel_launch(void* const* d_in, const int* in_sizes, int n_in,
                              void* d_out, int out_size, void* d_ws, size_t ws_size,
                              hipStream_t stream) {
  const float* x = (const float*)d_in[0];
  const float* Wqkv = (const float*)d_in[1];
  const float* bqkv = (const float*)d_in[2];
  const float* Wout = (const float*)d_in[3];
  const float* bout = (const float*)d_in[4];
  float* out = (float*)d_out;

  char* ws = (char*)d_ws;
  u16* xb  = (u16*)(ws);                    // 16 MB  x bf16 [8192][1024]
  u16* wqt = (u16*)(ws + 16777216);         //  6 MB  Wqkv^T bf16 [3072][1024]
  u16* wot = (u16*)(ws + 23068672);         //  2 MB  Wout^T bf16 [1024][1024]
  u16* Qb  = (u16*)(ws + 25165824);         // 48 MB  QKV bf16 [3][4][16][2048][64]
  u16* Kb  = Qb + 8388608;
  u16* Vb  = Kb + 8388608;
  u16* Vt  = (u16*)(ws + 75497472);         // 16 MB  V^T tiled bf16 [64bh][32kt][64d][64k]
  u16* ctx = (u16*)(ws + 92274688);         // 16 MB  attention out bf16 [8192][1024]

  cast_x_kernel<<<8192, 256, 0, stream>>>(x, xb);
  tcast_kernel<<<dim3(96, 32), 256, 0, stream>>>(Wqkv, wqt, 1024, 3072);
  tcast_kernel<<<dim3(32, 32), 256, 0, stream>>>(Wout, wot, 1024, 1024);
  gemm_qkv_kernel<<<dim3(24, 64), 256, 0, stream>>>(xb, wqt, bqkv, Qb);
  vtrans_kernel<<<dim3(32, 64), 256, 0, stream>>>(Vb, Vt);
  attn_kernel<<<dim3(8, 16, 4), 512, 0, stream>>>(Qb, Kb, Vt, ctx);
  gemm_proj_kernel<<<dim3(8, 64), 256, 0, stream>>>(ctx, wot, bout, out);
}

// Round 4
// 261.863 us; speedup vs baseline: 1.0673x; 1.0673x over previous
//
#include <hip/hip_runtime.h>
#include <hip/hip_bf16.h>
#include <string.h>

// CausalSelfAttention on MI355X (gfx950), bf16 MFMA pipeline.
// R13: attn reverted to R9 verbatim (proven 80.8us; R11/R12 fusion had a
//   deterministic logic bug — identical absmax across two sync protocols —
//   parked). GEMMs moved BK 32->64: halves barrier/drain pairs per K-sweep
//   (the 2-phase structure's dominant cost), with chunk-XOR LDS swizzle
//   (inverse-swizzled global source + swizzled ds_read, linear gload_lds
//   dest — same map as the attn K/V staging) to keep reads conflict-free.
// D=1024, H=16, Hd=64, B=4, T=2048.

typedef unsigned short u16;
typedef unsigned int u32;
typedef __bf16 bf16x8 __attribute__((ext_vector_type(8)));
typedef float f32x4 __attribute__((ext_vector_type(4)));

#define MFMA16(a, b, c) __builtin_amdgcn_mfma_f32_16x16x32_bf16((a), (b), (c), 0, 0, 0)

__device__ __forceinline__ u16 f2bf(float f) {
  unsigned u = __float_as_uint(f);
  u += 0x7fffu + ((u >> 16) & 1u);  // RNE
  return (u16)(u >> 16);
}

__device__ __forceinline__ u32 pk2bf(float a, float b) {
  __hip_bfloat162 h = __float22bfloat162_rn(make_float2(a, b));  // v_cvt_pk_bf16_f32
  u32 r;
  memcpy(&r, &h, 4);  // register-level no-op
  return r;
}

__device__ __forceinline__ void gload_lds16(const void* g, void* l) {
  __builtin_amdgcn_global_load_lds((const __attribute__((address_space(1))) void*)g,
                                   (__attribute__((address_space(3))) void*)l, 16, 0, 0);
}

// ---------------- cast x (fp32 -> bf16), 4 elems/thread ----------------
__global__ __launch_bounds__(256) void cast_x_kernel(const float* __restrict__ x,
                                                     u16* __restrict__ xb) {
  int i = blockIdx.x * 256 + threadIdx.x;
  float4 v = ((const float4*)x)[i];
  ushort4 o;
  o.x = f2bf(v.x); o.y = f2bf(v.y); o.z = f2bf(v.z); o.w = f2bf(v.w);
  ((ushort4*)xb)[i] = o;
}

// ---------------- transpose-cast W [K][N] fp32 -> Wt [N][K] bf16 ----------------
__global__ __launch_bounds__(256) void tcast_kernel(const float* __restrict__ W,
                                                    u16* __restrict__ Wt, int K, int N) {
  __shared__ float tile[32][33];
  int n0 = blockIdx.x * 32, k0 = blockIdx.y * 32;
  int tx = threadIdx.x & 31, ty = threadIdx.x >> 5;  // 32 x 8
#pragma unroll
  for (int i = 0; i < 4; i++) {
    int k = ty + i * 8;
    tile[k][tx] = W[(size_t)(k0 + k) * N + n0 + tx];
  }
  __syncthreads();
#pragma unroll
  for (int i = 0; i < 4; i++) {
    int n = ty + i * 8;
    Wt[(size_t)(n0 + n) * K + k0 + tx] = f2bf(tile[tx][n]);
  }
}

// ---------------- QKV GEMM: C[8192][3072] = xb @ Wqkvt^T + bias, scatter to Q/K/V ----------------
// BK=64: 16 K-steps (half the barriers of BK=32). LDS tiles [128][64] with
// chunk-XOR swizzle: LDS position p of row r holds global chunk p^(r&7)
// (involution), staged via inverse-swizzled SOURCE address (linear gload_lds
// dest), read back with the same XOR -> ds_read_b128 2 lanes/bank (free).
// Q (first 1024 output cols) scaled by log2(e)/8 so attention can use raw
// v_exp_f32 (= 2^x) with no per-score multiply.
__global__ __launch_bounds__(256) void gemm_qkv_kernel(const u16* __restrict__ A,
                                                       const u16* __restrict__ Bt,
                                                       const float* __restrict__ bias,
                                                       u16* __restrict__ QKV) {
  __shared__ u16 As[128 * 64];  // 16 KB
  __shared__ u16 Bs[128 * 64];  // 16 KB
  const int tid = threadIdx.x, w = tid >> 6, lane = tid & 63;
  const int g = lane >> 4, c = lane & 15;
  const int wr = w >> 1, wc = w & 1;
  const int m0 = blockIdx.y * 128, n0 = blockIdx.x * 128;
  const int srow = lane >> 3;                 // 0..7 within 8-row group
  const int sch = (lane & 7) ^ srow;          // inverse-swizzled source chunk
  const int cx = c & 7;                       // read-side row&7

  f32x4 acc[4][4];
#pragma unroll
  for (int i = 0; i < 4; i++)
#pragma unroll
    for (int j = 0; j < 4; j++) acc[i][j] = (f32x4){0.f, 0.f, 0.f, 0.f};

  for (int k0 = 0; k0 < 1024; k0 += 64) {
    __syncthreads();
#pragma unroll
    for (int i = 0; i < 4; i++) {
      int row = w * 32 + i * 8;  // wave stages rows w*32..w*32+31 (8/instr)
      gload_lds16(A + (size_t)(m0 + row + srow) * 1024 + k0 + sch * 8,
                  (char*)As + row * 128);
      gload_lds16(Bt + (size_t)(n0 + row + srow) * 1024 + k0 + sch * 8,
                  (char*)Bs + row * 128);
    }
    __syncthreads();

#pragma unroll
    for (int kk = 0; kk < 2; kk++) {
      bf16x8 af[4], bf[4];
#pragma unroll
      for (int mt = 0; mt < 4; mt++)
        af[mt] = *(const bf16x8*)(As + (wr * 64 + mt * 16 + c) * 64 + ((kk * 4 + g) ^ cx) * 8);
#pragma unroll
      for (int nt = 0; nt < 4; nt++)
        bf[nt] = *(const bf16x8*)(Bs + (wc * 64 + nt * 16 + c) * 64 + ((kk * 4 + g) ^ cx) * 8);
#pragma unroll
      for (int mt = 0; mt < 4; mt++)
#pragma unroll
        for (int nt = 0; nt < 4; nt++) acc[mt][nt] = MFMA16(af[mt], bf[nt], acc[mt][nt]);
    }
  }

  const float qscale = (n0 < 1024) ? 0.18033688011112042f : 1.0f;  // log2(e)/8
  float bn[4];
#pragma unroll
  for (int nt = 0; nt < 4; nt++) bn[nt] = bias[n0 + wc * 64 + nt * 16 + c];
#pragma unroll
  for (int mt = 0; mt < 4; mt++) {
#pragma unroll
    for (int r = 0; r < 4; r++) {
      int m = m0 + wr * 64 + mt * 16 + g * 4 + r;  // token index
      int bb = m >> 11, t = m & 2047;
#pragma unroll
      for (int nt = 0; nt < 4; nt++) {
        int n = n0 + wc * 64 + nt * 16 + c;
        int which = n >> 10, rem = n & 1023, h = rem >> 6, d = rem & 63;
        float v = (acc[mt][nt][r] + bn[nt]) * qscale;
        QKV[(size_t)which * 8388608 + (((size_t)(bb * 16 + h) * 2048 + t) * 64 + d)] = f2bf(v);
      }
    }
  }
}

// ---------------- V transpose: V[bh][2048][64] -> Vt tiled [bh][kt][64d][64k] ----------------
__global__ __launch_bounds__(256) void vtrans_kernel(const u16* __restrict__ V,
                                                     u16* __restrict__ Vt) {
  __shared__ u16 tile[64][65];
  int bh = blockIdx.y;
  int kt = blockIdx.x;
  int t0 = kt * 64;
  int tx = threadIdx.x & 63, ty = threadIdx.x >> 6;  // 64 x 4
  const u16* src = V + ((size_t)bh * 2048 + t0) * 64;
#pragma unroll
  for (int i = 0; i < 16; i++) {
    int tr = i * 4 + ty;
    tile[tr][tx] = src[tr * 64 + tx];
  }
  __syncthreads();
  u16* dst = Vt + ((size_t)(bh * 32 + kt)) * 4096;  // [64d][64k] tile
#pragma unroll
  for (int i = 0; i < 16; i++) {
    int d = i * 4 + ty;
    dst[d * 64 + tx] = tile[tx][d];
  }
}

// ---------------- flash attention: paired 128-row q-tiles, 8 waves x 16 q-rows ----------------
// grid (8 pairs, 16 heads, 4 batch), 512 threads (8 waves). Block handles
// q-tiles p and 15-p (128 rows each) sequentially: 34 uniform rounds.
// Wave w owns q-rows tile_base + w*16 .. +16. K/V staged in LDS dbuf (one
// gload each per wave per round), one barrier per round. S^T = mfma(K, Q);
// p = exp2(s) (Q pre-scaled by log2e/8); l via ones-MFMA psum; packed P/ctx.
__global__ __launch_bounds__(512, 4) void attn_kernel(const u16* __restrict__ Q,
                                                      const u16* __restrict__ K,
                                                      const u16* __restrict__ Vt,
                                                      u16* __restrict__ ctx) {
  const int pr = blockIdx.x;          // 0..7
  const int qtA = pr, qtB = 15 - pr;  // paired 128-row q-tiles
  const int h = blockIdx.y, b = blockIdx.z;
  const int bh = b * 16 + h;
  const int tid = threadIdx.x, w = tid >> 6, lane = tid & 63;
  const int g = lane >> 4, c = lane & 15;

  const u16* Kg = K + (size_t)bh * 2048 * 64;   // [T][64]
  const u16* Vg = Vt + (size_t)bh * 32 * 4096;  // tiled [kt][64d][64k]

  __shared__ u16 Ks[2][64 * 64];   // K dbuf, XOR-swizzled chunks (16 KB)
  __shared__ u16 Vs[2][64 * 64];   // V dbuf (16 KB)
  __shared__ u32 Pw[8][16 * 32];   // wave-private packed P^T (16 KB)
  u32* pw = Pw[w];

  // staging lane map (verified swizzle); wave w stages rows w*8..w*8+8
  const int srow = lane >> 3;
  const int schunk = (lane & 7) ^ (srow & 7);
  const int cx = c & 7;
  const int off0 = ((g ^ cx) * 8);        // chunk g   (u16 offset)
  const int off1 = (((g ^ cx) ^ 4) * 8);  // chunk g^4
  const int sw = cx << 2;                 // P-buffer 4-dword-block swizzle

  // constant all-ones A-fragment for the psum MFMA
  bf16x8 onesf;
#pragma unroll
  for (int i = 0; i < 8; i++) onesf[i] = (__bf16)1.0f;

  // Q B-fragments for tile A (wave's 16 q-rows; dims 0-31 / 32-63)
  const u16* QgA = Q + ((size_t)bh * 2048 + qtA * 128) * 64;
  bf16x8 aq0 = *(const bf16x8*)(QgA + (w * 16 + c) * 64 + g * 8);
  bf16x8 aq1 = *(const bf16x8*)(QgA + (w * 16 + c) * 64 + 32 + g * 8);

  // prologue: stage K/V tile 0 (1 gload each per wave)
  {
    int rbase = w * 8;
    gload_lds16(Kg + (size_t)(rbase + srow) * 64 + schunk * 8, (char*)(Ks[0]) + rbase * 128);
    gload_lds16(Vg + (size_t)(rbase + srow) * 64 + schunk * 8, (char*)(Vs[0]) + rbase * 128);
  }
  __syncthreads();

  f32x4 o[4], la;
#pragma unroll
  for (int nt = 0; nt < 4; nt++) o[nt] = (f32x4){0.f, 0.f, 0.f, 0.f};
  la = (f32x4){0.f, 0.f, 0.f, 0.f};

  const int nA = 2 * qtA + 2;  // rounds in tile A

  // normalize + packed 8B stores for one finished q-tile (wave's 16 rows)
  auto store_tile = [&](int qbase) {
    float inv = 1.f / la[0];
    int q = qbase + w * 16 + c;
    size_t base = ((size_t)(b * 2048 + q)) * 1024 + h * 64;
#pragma unroll
    for (int nt = 0; nt < 4; nt++) {
      u32 lo = pk2bf(o[nt][0] * inv, o[nt][1] * inv);
      u32 hi = pk2bf(o[nt][2] * inv, o[nt][3] * inv);
      *(uint2*)(ctx + base + nt * 16 + g * 4) = make_uint2(lo, hi);
    }
  };

  for (int r = 0; r < 34; r++) {
    if (r) __syncthreads();  // tile r staged; all waves done with buf r-1

    // prefetch round r+1's K/V tile (overlaps compute; drained at next barrier)
    if (r < 33) {
      const int ktn = (r + 1 < nA) ? (r + 1) : (r + 1 - nA);
      const int nb = (r + 1) & 1;
      int rbase = w * 8;
      gload_lds16(Kg + (size_t)ktn * 4096 + (size_t)(rbase + srow) * 64 + schunk * 8,
                  (char*)(Ks[nb]) + rbase * 128);
      gload_lds16(Vg + (size_t)ktn * 4096 + (size_t)(rbase + srow) * 64 + schunk * 8,
                  (char*)(Vs[nb]) + rbase * 128);
    }

    const bool inA = (r < nA);
    const int kt = inA ? r : (r - nA);
    const int qbase = inA ? qtA * 128 : qtB * 128;
    const int sb0 = qbase + w * 16;  // wave's first q-row
    const int kb = kt * 64;          // round's first key

    if (kb <= sb0 + 15) {  // wave-uniform: wave live this round
      const u16* Kb = Ks[r & 1];
      const u16* Vb = Vs[r & 1];

      // ---- S^T = K . Q^T : 4 key-tiles ----
      f32x4 sa[4];
#pragma unroll
      for (int nt = 0; nt < 4; nt++) {
        bf16x8 k0 = *(const bf16x8*)(Kb + (nt * 16 + c) * 64 + off0);
        bf16x8 k1 = *(const bf16x8*)(Kb + (nt * 16 + c) * 64 + off1);
        f32x4 z = (f32x4){0.f, 0.f, 0.f, 0.f};
        z = MFMA16(k0, aq0, z);  // A=K, B=Q -> S^T[key][q]
        z = MFMA16(k1, aq1, z);
        sa[nt] = z;
      }

      // ---- p = exp2(s), packed P^T write, B-frag read ----
      const bool domask = (kb + 63 > sb0);
      float pe[4][4];
#pragma unroll
      for (int nt = 0; nt < 4; nt++)
#pragma unroll
        for (int rr = 0; rr < 4; rr++) {
          float t = sa[nt][rr];
          if (domask && (kb + nt * 16 + g * 4 + rr) > (sb0 + c)) t = -1e30f;
          pe[nt][rr] = __builtin_amdgcn_exp2f(t);
        }
#pragma unroll
      for (int nt = 0; nt < 4; nt++) {
        u32 lo = pk2bf(pe[nt][0], pe[nt][1]);
        u32 hi = pk2bf(pe[nt][2], pe[nt][3]);
        *(uint2*)(pw + c * 32 + ((nt * 8 + g * 2) ^ sw)) = make_uint2(lo, hi);
      }
      bf16x8 pB0 = *(const bf16x8*)(pw + c * 32 + ((g * 4) ^ sw));
      bf16x8 pB1 = *(const bf16x8*)(pw + c * 32 + ((16 + g * 4) ^ sw));

      // ---- l += P @ 1 on the MFMA pipe ----
      la = MFMA16(onesf, pB0, la);
      la = MFMA16(onesf, pB1, la);

      // ---- O^T += V^T . P^T : 4 d-tiles ----
#pragma unroll
      for (int nt = 0; nt < 4; nt++) {
        bf16x8 v0 = *(const bf16x8*)(Vb + (nt * 16 + c) * 64 + off0);
        bf16x8 v1 = *(const bf16x8*)(Vb + (nt * 16 + c) * 64 + off1);
        o[nt] = MFMA16(v0, pB0, o[nt]);
        o[nt] = MFMA16(v1, pB1, o[nt]);
      }
    }

    // transition: tile A finished -> store, reset, swap to tile B's Q
    if (r == nA - 1) {
      store_tile(qtA * 128);
#pragma unroll
      for (int nt = 0; nt < 4; nt++) o[nt] = (f32x4){0.f, 0.f, 0.f, 0.f};
      la = (f32x4){0.f, 0.f, 0.f, 0.f};
      const u16* QgB = Q + ((size_t)bh * 2048 + qtB * 128) * 64;
      aq0 = *(const bf16x8*)(QgB + (w * 16 + c) * 64 + g * 8);
      aq1 = *(const bf16x8*)(QgB + (w * 16 + c) * 64 + 32 + g * 8);
    }
  }

  store_tile(qtB * 128);
}

// ---------------- out-proj GEMM: out[8192][1024] = ctx @ Woutt^T + bias (fp32 out) ----------------
// BK=64 + chunk-XOR swizzle, same as gemm_qkv.
__global__ __launch_bounds__(256) void gemm_proj_kernel(const u16* __restrict__ A,
                                                        const u16* __restrict__ Bt,
                                                        const float* __restrict__ bias,
                                                        float* __restrict__ out) {
  __shared__ u16 As[128 * 64];
  __shared__ u16 Bs[128 * 64];
  const int tid = threadIdx.x, w = tid >> 6, lane = tid & 63;
  const int g = lane >> 4, c = lane & 15;
  const int wr = w >> 1, wc = w & 1;
  const int m0 = blockIdx.y * 128, n0 = blockIdx.x * 128;
  const int srow = lane >> 3;
  const int sch = (lane & 7) ^ srow;
  const int cx = c & 7;

  f32x4 acc[4][4];
#pragma unroll
  for (int i = 0; i < 4; i++)
#pragma unroll
    for (int j = 0; j < 4; j++) acc[i][j] = (f32x4){0.f, 0.f, 0.f, 0.f};

  for (int k0 = 0; k0 < 1024; k0 += 64) {
    __syncthreads();
#pragma unroll
    for (int i = 0; i < 4; i++) {
      int row = w * 32 + i * 8;
      gload_lds16(A + (size_t)(m0 + row + srow) * 1024 + k0 + sch * 8,
                  (char*)As + row * 128);
      gload_lds16(Bt + (size_t)(n0 + row + srow) * 1024 + k0 + sch * 8,
                  (char*)Bs + row * 128);
    }
    __syncthreads();

#pragma unroll
    for (int kk = 0; kk < 2; kk++) {
      bf16x8 af[4], bf[4];
#pragma unroll
      for (int mt = 0; mt < 4; mt++)
        af[mt] = *(const bf16x8*)(As + (wr * 64 + mt * 16 + c) * 64 + ((kk * 4 + g) ^ cx) * 8);
#pragma unroll
      for (int nt = 0; nt < 4; nt++)
        bf[nt] = *(const bf16x8*)(Bs + (wc * 64 + nt * 16 + c) * 64 + ((kk * 4 + g) ^ cx) * 8);
#pragma unroll
      for (int mt = 0; mt < 4; mt++)
#pragma unroll
        for (int nt = 0; nt < 4; nt++) acc[mt][nt] = MFMA16(af[mt], bf[nt], acc[mt][nt]);
    }
  }

  float bn[4];
#pragma unroll
  for (int nt = 0; nt < 4; nt++) bn[nt] = bias[n0 + wc * 64 + nt * 16 + c];
#pragma unroll
  for (int mt = 0; mt < 4; mt++)
#pragma unroll
    for (int r = 0; r < 4; r++) {
      int m = m0 + wr * 64 + mt * 16 + g * 4 + r;
#pragma unroll
      for (int nt = 0; nt < 4; nt++) {
        int n = n0 + wc * 64 + nt * 16 + c;
        out[(size_t)m * 1024 + n] = acc[mt][nt][r] + bn[nt];
      }
    }
}

// ---------------- launch ----------------
extern "C" void kernel_launch(void* const* d_in, const int* in_sizes, int n_in,
                              void* d_out, int out_size, void* d_ws, size_t ws_size,
                              hipStream_t stream) {
  const float* x = (const float*)d_in[0];
  const float* Wqkv = (const float*)d_in[1];
  const float* bqkv = (const float*)d_in[2];
  const float* Wout = (const float*)d_in[3];
  const float* bout = (const float*)d_in[4];
  float* out = (float*)d_out;

  char* ws = (char*)d_ws;
  u16* xb  = (u16*)(ws);                    // 16 MB  x bf16 [8192][1024]
  u16* wqt = (u16*)(ws + 16777216);         //  6 MB  Wqkv^T bf16 [3072][1024]
  u16* wot = (u16*)(ws + 23068672);         //  2 MB  Wout^T bf16 [1024][1024]
  u16* Qb  = (u16*)(ws + 25165824);         // 48 MB  QKV bf16 [3][4][16][2048][64]
  u16* Kb  = Qb + 8388608;
  u16* Vb  = Kb + 8388608;
  u16* Vt  = (u16*)(ws + 75497472);         // 16 MB  V^T tiled bf16 [64bh][32kt][64d][64k]
  u16* ctx = (u16*)(ws + 92274688);         // 16 MB  attention out bf16 [8192][1024]

  cast_x_kernel<<<8192, 256, 0, stream>>>(x, xb);
  tcast_kernel<<<dim3(96, 32), 256, 0, stream>>>(Wqkv, wqt, 1024, 3072);
  tcast_kernel<<<dim3(32, 32), 256, 0, stream>>>(Wout, wot, 1024, 1024);
  gemm_qkv_kernel<<<dim3(24, 64), 256, 0, stream>>>(xb, wqt, bqkv, Qb);
  vtrans_kernel<<<dim3(32, 64), 256, 0, stream>>>(Vb, Vt);
  attn_kernel<<<dim3(8, 16, 4), 512, 0, stream>>>(Qb, Kb, Vt, ctx);
  gemm_proj_kernel<<<dim3(8, 64), 256, 0, stream>>>(ctx, wot, bout, out);
}